// Round 7
// baseline (133.371 us; speedup 1.0000x reference)
//
#include <hip/hip_runtime.h>

// KPConvInterSO3 via MFMA. N=16000, NB=32, A=4, K=15, CIN=COUT=32.
// R7: software-pipelined persistent-ish blocks. Block = 256 thr = 4 waves
// handles 16 queries as 4 groups of 4; grid = 1000 blocks (fully resident).
// Per group g: A(regs->LDS) | barrier | B(issue loads g+1; GEMM g) | barrier.
// Gather for g+1 is in flight during GEMM of g -> latency hidden in-block.
// x pre-converted to bf16 (4 MB, L2-resident) by prep_x; W pre-permuted by prep_w.

typedef short bf16x8 __attribute__((ext_vector_type(8)));
typedef float f32x4  __attribute__((ext_vector_type(4)));

// round-half-up bf16: 2 VALU ops. <=1 ulp difference vs RNE on ties.
__device__ __forceinline__ unsigned short f2bf(float f) {
    unsigned u = __builtin_bit_cast(unsigned, f);
    return (unsigned short)((u + 0x8000u) >> 16);
}

// pack two floats -> (bf(hi)<<16)|bf(lo) in 3 VALU ops via v_perm_b32
__device__ __forceinline__ unsigned pack2bf(float hi, float lo) {
    unsigned uh = __builtin_bit_cast(unsigned, hi) + 0x8000u;
    unsigned ul = __builtin_bit_cast(unsigned, lo) + 0x8000u;
    return __builtin_amdgcn_perm(uh, ul, 0x07060302u);
}

// Wp[kk][d][e] = bf16(W[k][c][d]), kcs = kk*32+e = c*16+k (k=15 -> 0 pad).
__global__ void prep_w(const float* __restrict__ W, unsigned short* __restrict__ Wp) {
    const int idx = blockIdx.x * 256 + threadIdx.x;   // 0..16383
    const int kk = idx >> 10, d = (idx >> 5) & 31, e = idx & 31;
    const int kcs = kk * 32 + e;
    const int c = kcs >> 4, k = kcs & 15;
    const float v = (k < 15) ? W[(k * 32 + c) * 32 + d] : 0.0f;
    Wp[idx] = f2bf(v);
}

// x (fp32, 2,048,000 floats) -> xb (bf16). 1000 blocks x 256 thr x 8 floats.
__global__ void prep_x(const float* __restrict__ x, unsigned short* __restrict__ xb) {
    const int i = (blockIdx.x * 256 + threadIdx.x) * 8;
    const float4 v0 = *(const float4*)&x[i];
    const float4 v1 = *(const float4*)&x[i + 4];
    uint4 u;
    u.x = pack2bf(v0.y, v0.x); u.y = pack2bf(v0.w, v0.z);
    u.z = pack2bf(v1.y, v1.x); u.w = pack2bf(v1.w, v1.z);
    *(uint4*)&xb[i] = u;
}

__global__ __launch_bounds__(256) void kpconv_mfma(
    const float* __restrict__ q_pts,    // [N,3]
    const float* __restrict__ s_pts,    // [M,3]
    const int*   __restrict__ inds,     // [N,32]
    const unsigned short* __restrict__ xb, // [M,4,32] bf16
    const float* __restrict__ kp,       // [15,3]
    const float* __restrict__ anchors,  // [4,3,3]
    const unsigned short* __restrict__ Wp, // [16][32][32] bf16 (permuted)
    float*       __restrict__ out)      // [N,4,32]
{
    // xa_s: [a][q][c][b_phys] bf16, 32KB; per-a 4KB slice aliased by wf during B
    // (wave-private, consumed before the end-of-B barrier -> safe w/ pipelining).
    __shared__ __align__(16) unsigned short xa_s[16384];
    // nbr: [q][b] float4, padded: float4 idx = q*36 + b + (b>>3). Single-buffered:
    // written in A(g) (after barrier2(g-1), all B(g-1) reads done), read in B(g).
    __shared__ __align__(16) float nbr[576];
    __shared__ __align__(16) float rk_s[256];   // [a][k] float4; k=15 -> (0,0,0,1e30)

    const int t    = threadIdx.x;
    const int nblk = blockIdx.x * 16;   // 16 queries per block

    // gather-phase lane roles (cooperative, all anchors)
    const int c4 = t & 7, bg = (t >> 3) & 7, qg = t >> 6;
    // compute-phase lane roles (wave = anchor)
    const int a = t >> 6, lane = t & 63, l15 = lane & 15, quad = lane >> 4;
    const int fc = (l15 >> 2) & 3;

    // ---- pipeline registers (filled in B(g-1)/prologue, consumed in A(g))
    uint2 gb[16];                       // gather: [anchor][row-of-4]
    int   pidx = 0;
    float psx = 0, psy = 0, psz = 0, pqx = 0, pqy = 0, pqz = 0;

    // ---------------- prologue: rk_s + loads for group 0 ----------------
    if (t >= 128 && t < 192) {
        const int j = t - 128;
        const int aa = j >> 4, k = j & 15;
        float4 v;
        if (k < 15) {
            const float kx = kp[k*3+0], ky = kp[k*3+1], kz = kp[k*3+2];
            const float* R = anchors + aa * 9;
            v.x = R[0]*kx + R[1]*ky + R[2]*kz;
            v.y = R[3]*kx + R[4]*ky + R[5]*kz;
            v.z = R[6]*kx + R[7]*ky + R[8]*kz;
            v.w = v.x*v.x + v.y*v.y + v.z*v.z;
        } else {
            v.x = 0.0f; v.y = 0.0f; v.z = 0.0f; v.w = 1e30f;  // kills k=15 row
        }
        *(float4*)&rk_s[(aa * 16 + k) * 4] = v;
    }
    {
        const int4 rows = *(const int4*)&inds[(nblk + qg) * 32 + 4 * bg];
        #pragma unroll
        for (int aa = 0; aa < 4; ++aa) {
            gb[aa*4+0] = *(const uint2*)&xb[rows.x * 128 + aa * 32 + c4 * 4];
            gb[aa*4+1] = *(const uint2*)&xb[rows.y * 128 + aa * 32 + c4 * 4];
            gb[aa*4+2] = *(const uint2*)&xb[rows.z * 128 + aa * 32 + c4 * 4];
            gb[aa*4+3] = *(const uint2*)&xb[rows.w * 128 + aa * 32 + c4 * 4];
        }
        if (t < 128) {
            const int qq2 = t >> 5, b = t & 31;
            pidx = inds[(nblk + qq2) * 32 + b];
            psx = s_pts[pidx*3+0]; psy = s_pts[pidx*3+1]; psz = s_pts[pidx*3+2];
            pqx = q_pts[(nblk+qq2)*3+0]; pqy = q_pts[(nblk+qq2)*3+1]; pqz = q_pts[(nblk+qq2)*3+2];
        }
    }

    #pragma unroll
    for (int g = 0; g < 4; ++g) {
        const int n0 = nblk + g * 4;

        // ---------------- A: consume pipeline regs into LDS ----------------
        if (t < 128) {
            const int qq2 = t >> 5, b = t & 31;
            const float nx = psx - pqx, ny = psy - pqy, nz = psz - pqz;
            float4 v; v.x = nx; v.y = ny; v.z = nz; v.w = nx*nx + ny*ny + nz*nz;
            *(float4*)&nbr[(qq2 * 36 + b + (b >> 3)) * 4] = v;
        }
        {
            // b-block swizzle: b' = (b&7) | (((b>>3) ^ (c>>2&3)) << 3)
            const int bb  = 4 * (bg & 1);
            const int blk = 8 * ((bg >> 1) ^ (c4 & 3));
            unsigned short* base = &xa_s[(qg * 32) * 32 + blk + bb];
            #pragma unroll
            for (int aa = 0; aa < 4; ++aa) {
                unsigned short* pa = base + aa * 4096;
                uint2 w;
                w.x = __builtin_amdgcn_perm(gb[aa*4+1].x, gb[aa*4+0].x, 0x05040100u);
                w.y = __builtin_amdgcn_perm(gb[aa*4+3].x, gb[aa*4+2].x, 0x05040100u);
                *(uint2*)&pa[(4 * c4 + 0) * 32] = w;
                w.x = __builtin_amdgcn_perm(gb[aa*4+1].x, gb[aa*4+0].x, 0x07060302u);
                w.y = __builtin_amdgcn_perm(gb[aa*4+3].x, gb[aa*4+2].x, 0x07060302u);
                *(uint2*)&pa[(4 * c4 + 1) * 32] = w;
                w.x = __builtin_amdgcn_perm(gb[aa*4+1].y, gb[aa*4+0].y, 0x05040100u);
                w.y = __builtin_amdgcn_perm(gb[aa*4+3].y, gb[aa*4+2].y, 0x05040100u);
                *(uint2*)&pa[(4 * c4 + 2) * 32] = w;
                w.x = __builtin_amdgcn_perm(gb[aa*4+1].y, gb[aa*4+0].y, 0x07060302u);
                w.y = __builtin_amdgcn_perm(gb[aa*4+3].y, gb[aa*4+2].y, 0x07060302u);
                *(uint2*)&pa[(4 * c4 + 3) * 32] = w;
            }
        }
        __syncthreads();   // xa_s + nbr (+ rk_s on g=0) visible

        // ---------------- B: issue loads for g+1, then GEMM on g ----------------
        if (g < 3) {
            const int n1 = n0 + 4;
            const int4 rows = *(const int4*)&inds[(n1 + qg) * 32 + 4 * bg];
            #pragma unroll
            for (int aa = 0; aa < 4; ++aa) {
                gb[aa*4+0] = *(const uint2*)&xb[rows.x * 128 + aa * 32 + c4 * 4];
                gb[aa*4+1] = *(const uint2*)&xb[rows.y * 128 + aa * 32 + c4 * 4];
                gb[aa*4+2] = *(const uint2*)&xb[rows.z * 128 + aa * 32 + c4 * 4];
                gb[aa*4+3] = *(const uint2*)&xb[rows.w * 128 + aa * 32 + c4 * 4];
            }
            if (t < 128) {
                const int qq2 = t >> 5, b = t & 31;
                pidx = inds[(n1 + qq2) * 32 + b];
                psx = s_pts[pidx*3+0]; psy = s_pts[pidx*3+1]; psz = s_pts[pidx*3+2];
                pqx = q_pts[(n1+qq2)*3+0]; pqy = q_pts[(n1+qq2)*3+1]; pqz = q_pts[(n1+qq2)*3+2];
            }
        }

        const float4 r4 = *(const float4*)&rk_s[(a * 16 + l15) * 4];
        unsigned short* wfb = &xa_s[a * 4096];

        // GEMM1: per q, wf[k,c] = sum_b aw[b,k]*x[b,c]; A-frag (weights) in regs.
        #pragma unroll
        for (int q = 0; q < 4; ++q) {
            float w8[8];
            #pragma unroll
            for (int j = 0; j < 8; ++j) {
                const int b = quad * 8 + j;
                const float4 nb = *(const float4*)&nbr[(q * 36 + b + (b >> 3)) * 4];
                const float dot = fmaf(nb.x, r4.x, fmaf(nb.y, r4.y, nb.z * r4.z));
                const float sq  = fmaf(-2.0f, dot, nb.w + r4.w);
                const float d   = sqrtf(fmaxf(sq, 1e-12f));
                w8[j] = fmaxf(fmaf(d, -(1.0f / 0.6f), 1.0f), 0.0f);
            }
            uint4 uu;
            uu.x = pack2bf(w8[1], w8[0]); uu.y = pack2bf(w8[3], w8[2]);
            uu.z = pack2bf(w8[5], w8[4]); uu.w = pack2bf(w8[7], w8[6]);
            const bf16x8 afr = __builtin_bit_cast(bf16x8, uu);

            const bf16x8 b0 = *(const bf16x8*)&xa_s[((a*4 + q)*32 + l15)      * 32 + 8 * (quad ^ fc)];
            const bf16x8 b1 = *(const bf16x8*)&xa_s[((a*4 + q)*32 + l15 + 16) * 32 + 8 * (quad ^ fc)];
            f32x4 d0 = {0.f,0.f,0.f,0.f}, d1 = {0.f,0.f,0.f,0.f};
            d0 = __builtin_amdgcn_mfma_f32_16x16x32_bf16(afr, b0, d0, 0, 0, 0);
            d1 = __builtin_amdgcn_mfma_f32_16x16x32_bf16(afr, b1, d1, 0, 0, 0);
            // D: col c = l15 (+16), rows k = quad*4+reg. Store at q*512 + (kcs^(q*16)).
            uint2 s0, s1;
            s0.x = pack2bf(d0[1], d0[0]); s0.y = pack2bf(d0[3], d0[2]);
            s1.x = pack2bf(d1[1], d1[0]); s1.y = pack2bf(d1[3], d1[2]);
            *(uint2*)&wfb[q*512 + (( l15       * 16 + quad * 4) ^ (q * 16))] = s0;
            *(uint2*)&wfb[q*512 + (((l15 + 16) * 16 + quad * 4) ^ (q * 16))] = s1;
        }
        // no barrier: xa_s[a] slice is wave-private; DS in-order per wave

        // GEMM2: out[q,d] = sum_{kc} wf[q,kc] * W[kc,d]; A rows m -> q = m&3
        const int qq = l15 & 3;
        f32x4 o0 = {0.f,0.f,0.f,0.f}, o1 = {0.f,0.f,0.f,0.f};
        #pragma unroll
        for (int kk = 0; kk < 16; ++kk) {
            const bf16x8 a2 = *(const bf16x8*)&wfb[qq*512 + ((kk*32 + quad*8) ^ (qq*16))];
            const bf16x8 w0 = *(const bf16x8*)&Wp[kk*1024 + l15*32 + quad*8];
            const bf16x8 w1 = *(const bf16x8*)&Wp[kk*1024 + (l15+16)*32 + quad*8];
            o0 = __builtin_amdgcn_mfma_f32_16x16x32_bf16(a2, w0, o0, 0, 0, 0);
            o1 = __builtin_amdgcn_mfma_f32_16x16x32_bf16(a2, w1, o1, 0, 0, 0);
        }
        // D: col d = l15 (+16), rows = quad*4+reg; quad 0 rows 0..3 = q
        if (quad == 0) {
            #pragma unroll
            for (int r = 0; r < 4; ++r) {
                out[((n0 + r) * 4 + a) * 32 + l15]      = o0[r];
                out[((n0 + r) * 4 + a) * 32 + 16 + l15] = o1[r];
            }
        }

        if (g < 3) __syncthreads();   // protect xa_s/nbr reuse; gather g+1 already
                                      // ~3k cycles in flight -> vmcnt drain ~free
    }
}

extern "C" void kernel_launch(void* const* d_in, const int* in_sizes, int n_in,
                              void* d_out, int out_size, void* d_ws, size_t ws_size,
                              hipStream_t stream) {
    const float* q_pts   = (const float*)d_in[0];
    const float* s_pts   = (const float*)d_in[1];
    const int*   inds    = (const int*)d_in[2];
    const float* x       = (const float*)d_in[3];
    const float* kp      = (const float*)d_in[4];
    const float* anchors = (const float*)d_in[5];
    const float* weights = (const float*)d_in[6];
    float*       out     = (float*)d_out;

    unsigned short* Wp = (unsigned short*)d_ws;                       // 32 KB
    unsigned short* xb = (unsigned short*)((char*)d_ws + (1 << 16));  // 4 MB

    prep_w<<<dim3(64),   dim3(256), 0, stream>>>(weights, Wp);
    prep_x<<<dim3(1000), dim3(256), 0, stream>>>(x, xb);
    kpconv_mfma<<<dim3(1000), dim3(256), 0, stream>>>(
        q_pts, s_pts, inds, xb, kp, anchors, Wp, out);
}

// Round 8
// 123.637 us; speedup vs baseline: 1.0787x; 1.0787x over previous
//
#include <hip/hip_runtime.h>

// KPConvInterSO3 via MFMA. N=16000, NB=32, A=4, K=15, CIN=COUT=32.
// Block = 256 threads = 4 waves; block handles 4 queries; wave w owns anchor w.
// R8: influence weights via cross-MFMA: sq[b,k] = k2 + n.(-2r) + n2 as a
// 16x16x32 dot with bf16 hi/lo-split operands (fp32-grade sq). Replaces the
// 32 bcast ds_reads + ~120 VALU weight compute per wave with 8 ds_reads + 8 MFMA.
// GEMM1 per (q,a): wf[k,c] = sum_b aw[b,k] x[b,c]; GEMM2: out = wf . Wp.
// x pre-converted to bf16 (4 MB, L2-resident); W pre-permuted.

typedef short bf16x8 __attribute__((ext_vector_type(8)));
typedef float f32x4  __attribute__((ext_vector_type(4)));

// round-half-up bf16: 2 VALU ops. <=1 ulp vs RNE on ties.
__device__ __forceinline__ unsigned short f2bf(float f) {
    unsigned u = __builtin_bit_cast(unsigned, f);
    return (unsigned short)((u + 0x8000u) >> 16);
}
__device__ __forceinline__ float bf2f(unsigned short h) {
    return __builtin_bit_cast(float, (unsigned)h << 16);
}
// pack two floats -> (bf(hi)<<16)|bf(lo) in 3 VALU ops via v_perm_b32
__device__ __forceinline__ unsigned pack2bf(float hi, float lo) {
    unsigned uh = __builtin_bit_cast(unsigned, hi) + 0x8000u;
    unsigned ul = __builtin_bit_cast(unsigned, lo) + 0x8000u;
    return __builtin_amdgcn_perm(uh, ul, 0x07060302u);
}
// hi/lo split: v ~= bf(h) + bf(l), residual ~2^-18 rel
__device__ __forceinline__ void bfsplit(float v, unsigned short& h, unsigned short& l) {
    h = f2bf(v);
    l = f2bf(v - bf2f(h));
}

// Wp[kk][d][e] = bf16(W[k][c][d]), kcs = kk*32+e = c*16+k (k=15 -> 0 pad).
__global__ void prep_w(const float* __restrict__ W, unsigned short* __restrict__ Wp) {
    const int idx = blockIdx.x * 256 + threadIdx.x;   // 0..16383
    const int kk = idx >> 10, d = (idx >> 5) & 31, e = idx & 31;
    const int kcs = kk * 32 + e;
    const int c = kcs >> 4, k = kcs & 15;
    const float v = (k < 15) ? W[(k * 32 + c) * 32 + d] : 0.0f;
    Wp[idx] = f2bf(v);
}

// x (fp32, 2,048,000 floats) -> xb (bf16). 1000 blocks x 256 thr x 8 floats.
__global__ void prep_x(const float* __restrict__ x, unsigned short* __restrict__ xb) {
    const int i = (blockIdx.x * 256 + threadIdx.x) * 8;
    const float4 v0 = *(const float4*)&x[i];
    const float4 v1 = *(const float4*)&x[i + 4];
    uint4 u;
    u.x = pack2bf(v0.y, v0.x); u.y = pack2bf(v0.w, v0.z);
    u.z = pack2bf(v1.y, v1.x); u.w = pack2bf(v1.w, v1.z);
    *(uint4*)&xb[i] = u;
}

__global__ __launch_bounds__(256) void kpconv_mfma(
    const float* __restrict__ q_pts,    // [N,3]
    const float* __restrict__ s_pts,    // [M,3]
    const int*   __restrict__ inds,     // [N,32]
    const unsigned short* __restrict__ xb, // [M,4,32] bf16
    const float* __restrict__ kp,       // [15,3]
    const float* __restrict__ anchors,  // [4,3,3]
    const unsigned short* __restrict__ Wp, // [16][32][32] bf16 (permuted)
    float*       __restrict__ out)      // [N,4,32]
{
    // xa_s: [a][q][c][b_slot] bf16, 32KB; per-a 4KB slice aliased by wf after
    // GEMM1 (wave-private, in-order DS). b_slot permutation (see below).
    __shared__ __align__(16) unsigned short xa_s[16384];
    // nbr32: per (q,b) the 16-slot bf16 A-row for the cross-MFMA, row stride
    // 24 shorts (48B) for bank spread. 6 KB.
    __shared__ __align__(16) unsigned short nbr32[3072];
    __shared__ __align__(16) unsigned short zz[128];   // 256B zeros (quads 2-3 A-frag)

    const int t  = threadIdx.x;
    const int n0 = blockIdx.x * 4;
    const int a = t >> 6, lane = t & 63, l15 = lane & 15, quad = lane >> 4;

    // ---- prologue: per-lane B-frag (constant) for the cross-MFMA ----
    // kdim slots: 0:k2h 1:k2l 2:Rxh 3:Rxl 4:Rxh 5:Ryh 6:Ryl 7:Ryh |
    //             8:Rzh 9:Rzl 10:Rzh 11:1 12:1 13..15:0    (R = -2*r)
    bf16x8 rkb;
    {
        float rx = 0.f, ry = 0.f, rz = 0.f, k2 = 1e30f;   // k=15 sentinel -> w=0
        if (l15 < 15) {
            const float kx = kp[l15*3+0], ky = kp[l15*3+1], kz = kp[l15*3+2];
            const float* R = anchors + a * 9;
            rx = R[0]*kx + R[1]*ky + R[2]*kz;
            ry = R[3]*kx + R[4]*ky + R[5]*kz;
            rz = R[6]*kx + R[7]*ky + R[8]*kz;
            k2 = rx*rx + ry*ry + rz*rz;
        }
        unsigned short k2h,k2l, Rxh,Rxl, Ryh,Ryl, Rzh,Rzl;
        bfsplit(k2, k2h, k2l);
        bfsplit(-2.0f*rx, Rxh, Rxl);
        bfsplit(-2.0f*ry, Ryh, Ryl);
        bfsplit(-2.0f*rz, Rzh, Rzl);
        const unsigned ONE = 0x3F80u;
        uint4 u;
        if (quad == 0) {
            u.x = (unsigned)k2h | ((unsigned)k2l << 16);
            u.y = (unsigned)Rxh | ((unsigned)Rxl << 16);
            u.z = (unsigned)Rxh | ((unsigned)Ryh << 16);
            u.w = (unsigned)Ryl | ((unsigned)Ryh << 16);
        } else if (quad == 1) {
            u.x = (unsigned)Rzh | ((unsigned)Rzl << 16);
            u.y = (unsigned)Rzh | (ONE << 16);
            u.z = ONE;
            u.w = 0u;
        } else {
            u.x = u.y = u.z = u.w = 0u;
        }
        rkb = __builtin_bit_cast(bf16x8, u);
    }

    // ---- stage nbr32 A-rows (t<128) + zero block (t 128..143) ----
    if (t < 128) {
        const int q = t >> 5, b = t & 31;
        const int idx = inds[(n0 + q) * 32 + b];
        const float nx = s_pts[idx*3+0] - q_pts[(n0+q)*3+0];
        const float ny = s_pts[idx*3+1] - q_pts[(n0+q)*3+1];
        const float nz = s_pts[idx*3+2] - q_pts[(n0+q)*3+2];
        const float n2 = nx*nx + ny*ny + nz*nz;
        unsigned short nxh,nxl, nyh,nyl, nzh,nzl, n2h,n2l;
        bfsplit(nx, nxh, nxl); bfsplit(ny, nyh, nyl);
        bfsplit(nz, nzh, nzl); bfsplit(n2, n2h, n2l);
        const unsigned ONE = 0x3F80u;
        // A slots: 0:1 1:1 2:nxh 3:nxh 4:nxl 5:nyh 6:nyh 7:nyl |
        //          8:nzh 9:nzh 10:nzl 11:n2h 12:n2l 13..15:0
        uint4 lo, hi;
        lo.x = ONE | (ONE << 16);
        lo.y = (unsigned)nxh | ((unsigned)nxh << 16);
        lo.z = (unsigned)nxl | ((unsigned)nyh << 16);
        lo.w = (unsigned)nyh | ((unsigned)nyl << 16);
        hi.x = (unsigned)nzh | ((unsigned)nzh << 16);
        hi.y = (unsigned)nzl | ((unsigned)n2h << 16);
        hi.z = (unsigned)n2l;
        hi.w = 0u;
        unsigned short* p = &nbr32[(q * 32 + b) * 24];
        *(uint4*)(p)     = lo;
        *(uint4*)(p + 8) = hi;
    } else if (t < 144) {
        *(uint4*)&zz[(t - 128) * 8] = make_uint4(0,0,0,0);
    }

    // ---- P2: gather xb -> xa_s (register transpose) ----
    // logical b = 4*bg+i  ->  slot = ((bg&3)^fc)*8 + (bg>>2)*4 + i, fc = c4&3.
    // (octet Q=bg&3 matches GEMM1 quad; half h=bg>>2 picks jj 0-3 vs 4-7.)
    {
        const int c4 = t & 7, bg = (t >> 3) & 7, q = t >> 6;
        const int4 rows = *(const int4*)&inds[(n0 + q) * 32 + 4 * bg];
        const int fcs   = c4 & 3;
        const int slotb = ((bg & 3) ^ fcs) * 8 + (bg >> 2) * 4;
        unsigned short* base = &xa_s[(q * 32) * 32 + slotb];
        #pragma unroll
        for (int aa = 0; aa < 4; ++aa) {
            const uint2 r0 = *(const uint2*)&xb[rows.x * 128 + aa * 32 + c4 * 4];
            const uint2 r1 = *(const uint2*)&xb[rows.y * 128 + aa * 32 + c4 * 4];
            const uint2 r2 = *(const uint2*)&xb[rows.z * 128 + aa * 32 + c4 * 4];
            const uint2 r3 = *(const uint2*)&xb[rows.w * 128 + aa * 32 + c4 * 4];
            unsigned short* pa = base + aa * 4096;
            uint2 w;
            w.x = __builtin_amdgcn_perm(r1.x, r0.x, 0x05040100u);
            w.y = __builtin_amdgcn_perm(r3.x, r2.x, 0x05040100u);
            *(uint2*)&pa[(4 * c4 + 0) * 32] = w;
            w.x = __builtin_amdgcn_perm(r1.x, r0.x, 0x07060302u);
            w.y = __builtin_amdgcn_perm(r3.x, r2.x, 0x07060302u);
            *(uint2*)&pa[(4 * c4 + 1) * 32] = w;
            w.x = __builtin_amdgcn_perm(r1.y, r0.y, 0x05040100u);
            w.y = __builtin_amdgcn_perm(r3.y, r2.y, 0x05040100u);
            *(uint2*)&pa[(4 * c4 + 2) * 32] = w;
            w.x = __builtin_amdgcn_perm(r1.y, r0.y, 0x07060302u);
            w.y = __builtin_amdgcn_perm(r3.y, r2.y, 0x07060302u);
            *(uint2*)&pa[(4 * c4 + 3) * 32] = w;
        }
    }
    __syncthreads();

    // ---------------- Per-wave: anchor a = wave id ----------------
    const int fc = (l15 >> 2) & 3;
    unsigned short* wfb = &xa_s[a * 4096];
    const f32x4 zacc = {0.f, 0.f, 0.f, 0.f};

    #pragma unroll
    for (int q = 0; q < 4; ++q) {
        // cross-MFMA: sq[b][k] for b-halves 0..15 (s0) and 16..31 (s1).
        // A rows: quad0 = slots 0-7, quad1 = slots 8-15, quads 2-3 = zeros.
        const unsigned short* aX = (quad < 2)
            ? &nbr32[(q * 32 + l15) * 24 + (quad & 1) * 8]       : &zz[l15 * 8];
        const unsigned short* aY = (quad < 2)
            ? &nbr32[(q * 32 + 16 + l15) * 24 + (quad & 1) * 8]  : &zz[l15 * 8];
        const f32x4 s0 = __builtin_amdgcn_mfma_f32_16x16x32_bf16(*(const bf16x8*)aX, rkb, zacc, 0, 0, 0);
        const f32x4 s1 = __builtin_amdgcn_mfma_f32_16x16x32_bf16(*(const bf16x8*)aY, rkb, zacc, 0, 0, 0);
        // D: col k = l15, rows b = quad*4+reg (s0), 16+quad*4+reg (s1)
        float w8[8];
        #pragma unroll
        for (int j = 0; j < 4; ++j) {
            w8[j]     = fmaxf(fmaf(sqrtf(fmaxf(s0[j], 1e-12f)), -1.6666667f, 1.0f), 0.0f);
            w8[4 + j] = fmaxf(fmaf(sqrtf(fmaxf(s1[j], 1e-12f)), -1.6666667f, 1.0f), 0.0f);
        }
        uint4 uu;
        uu.x = pack2bf(w8[1], w8[0]); uu.y = pack2bf(w8[3], w8[2]);
        uu.z = pack2bf(w8[5], w8[4]); uu.w = pack2bf(w8[7], w8[6]);
        const bf16x8 afr = __builtin_bit_cast(bf16x8, uu);   // A[k=l15][b-octet(quad)]

        // GEMM1: B[b][c] from xa (slot-permuted to match), D: col c, rows k.
        const bf16x8 b0 = *(const bf16x8*)&xa_s[((a*4 + q)*32 + l15)      * 32 + 8 * (quad ^ fc)];
        const bf16x8 b1 = *(const bf16x8*)&xa_s[((a*4 + q)*32 + l15 + 16) * 32 + 8 * (quad ^ fc)];
        f32x4 d0 = zacc, d1 = zacc;
        d0 = __builtin_amdgcn_mfma_f32_16x16x32_bf16(afr, b0, d0, 0, 0, 0);
        d1 = __builtin_amdgcn_mfma_f32_16x16x32_bf16(afr, b1, d1, 0, 0, 0);
        // wf store at q*512 + (kcs ^ (q*16)), kcs = c*16 + k
        uint2 s0p, s1p;
        s0p.x = pack2bf(d0[1], d0[0]); s0p.y = pack2bf(d0[3], d0[2]);
        s1p.x = pack2bf(d1[1], d1[0]); s1p.y = pack2bf(d1[3], d1[2]);
        *(uint2*)&wfb[q*512 + (( l15       * 16 + quad * 4) ^ (q * 16))] = s0p;
        *(uint2*)&wfb[q*512 + (((l15 + 16) * 16 + quad * 4) ^ (q * 16))] = s1p;
    }
    // no barrier: xa_s[a] slice is wave-private; DS in-order per wave

    // GEMM2: out[q,d] = sum_{kc} wf[q,kc] * Wp[kc,d]; A rows m -> q = m&3
    const int qq = l15 & 3;
    f32x4 o0 = zacc, o1 = zacc;
    #pragma unroll
    for (int kk = 0; kk < 16; ++kk) {
        const bf16x8 a2 = *(const bf16x8*)&wfb[qq*512 + ((kk*32 + quad*8) ^ (qq*16))];
        const bf16x8 w0 = *(const bf16x8*)&Wp[kk*1024 + l15*32 + quad*8];
        const bf16x8 w1 = *(const bf16x8*)&Wp[kk*1024 + (l15+16)*32 + quad*8];
        o0 = __builtin_amdgcn_mfma_f32_16x16x32_bf16(a2, w0, o0, 0, 0, 0);
        o1 = __builtin_amdgcn_mfma_f32_16x16x32_bf16(a2, w1, o1, 0, 0, 0);
    }
    // D: col d = l15 (+16), rows = quad*4+reg; quad 0 rows 0..3 = q
    if (quad == 0) {
        #pragma unroll
        for (int r = 0; r < 4; ++r) {
            out[((n0 + r) * 4 + a) * 32 + l15]      = o0[r];
            out[((n0 + r) * 4 + a) * 32 + 16 + l15] = o1[r];
        }
    }
}

extern "C" void kernel_launch(void* const* d_in, const int* in_sizes, int n_in,
                              void* d_out, int out_size, void* d_ws, size_t ws_size,
                              hipStream_t stream) {
    const float* q_pts   = (const float*)d_in[0];
    const float* s_pts   = (const float*)d_in[1];
    const int*   inds    = (const int*)d_in[2];
    const float* x       = (const float*)d_in[3];
    const float* kp      = (const float*)d_in[4];
    const float* anchors = (const float*)d_in[5];
    const float* weights = (const float*)d_in[6];
    float*       out     = (float*)d_out;

    unsigned short* Wp = (unsigned short*)d_ws;                       // 32 KB
    unsigned short* xb = (unsigned short*)((char*)d_ws + (1 << 16));  // 4 MB

    prep_w<<<dim3(64),   dim3(256), 0, stream>>>(weights, Wp);
    prep_x<<<dim3(1000), dim3(256), 0, stream>>>(x, xb);
    kpconv_mfma<<<dim3(4000), dim3(256), 0, stream>>>(
        q_pts, s_pts, inds, xb, kp, anchors, Wp, out);
}

// Round 9
// 113.538 us; speedup vs baseline: 1.1747x; 1.0889x over previous
//
#include <hip/hip_runtime.h>

// KPConvInterSO3 via MFMA. N=16000, NB=32, A=4, K=15, CIN=COUT=32.
// Block = 256 threads = 4 waves; block handles 4 queries; wave w owns anchor w
// for GEMM1. R9: GEMM2 restructured — A rows = 16 (anchor,query) pairs, split
// across waves by (d-tile, kk-range): 32 MFMA + 32 Wp loads per BLOCK (was 128).
// Cross-wave partial reduction through 2KB LDS (aliases nbr32).
// Influence weights via cross-MFMA (R8), zz zero-block eliminated (B slots
// 16..31 are zero so quads 2-3 A-reads broadcast quads 0-1 addresses).
// x pre-converted to bf16 (4 MB, L2-resident); W pre-permuted to B-frag layout.

typedef short bf16x8 __attribute__((ext_vector_type(8)));
typedef float f32x4  __attribute__((ext_vector_type(4)));

// round-half-up bf16: 2 VALU ops. <=1 ulp vs RNE on ties.
__device__ __forceinline__ unsigned short f2bf(float f) {
    unsigned u = __builtin_bit_cast(unsigned, f);
    return (unsigned short)((u + 0x8000u) >> 16);
}
__device__ __forceinline__ float bf2f(unsigned short h) {
    return __builtin_bit_cast(float, (unsigned)h << 16);
}
// pack two floats -> (bf(hi)<<16)|bf(lo) in 3 VALU ops via v_perm_b32
__device__ __forceinline__ unsigned pack2bf(float hi, float lo) {
    unsigned uh = __builtin_bit_cast(unsigned, hi) + 0x8000u;
    unsigned ul = __builtin_bit_cast(unsigned, lo) + 0x8000u;
    return __builtin_amdgcn_perm(uh, ul, 0x07060302u);
}
// hi/lo split: v ~= bf(h) + bf(l), residual ~2^-18 rel
__device__ __forceinline__ void bfsplit(float v, unsigned short& h, unsigned short& l) {
    h = f2bf(v);
    l = f2bf(v - bf2f(h));
}

// Wp[kk][d][e] = bf16(W[k][c][d]), kcs = kk*32+e = c*16+k (k=15 -> 0 pad).
__global__ void prep_w(const float* __restrict__ W, unsigned short* __restrict__ Wp) {
    const int idx = blockIdx.x * 256 + threadIdx.x;   // 0..16383
    const int kk = idx >> 10, d = (idx >> 5) & 31, e = idx & 31;
    const int kcs = kk * 32 + e;
    const int c = kcs >> 4, k = kcs & 15;
    const float v = (k < 15) ? W[(k * 32 + c) * 32 + d] : 0.0f;
    Wp[idx] = f2bf(v);
}

// x (fp32, 2,048,000 floats) -> xb (bf16). 1000 blocks x 256 thr x 8 floats.
__global__ void prep_x(const float* __restrict__ x, unsigned short* __restrict__ xb) {
    const int i = (blockIdx.x * 256 + threadIdx.x) * 8;
    const float4 v0 = *(const float4*)&x[i];
    const float4 v1 = *(const float4*)&x[i + 4];
    uint4 u;
    u.x = pack2bf(v0.y, v0.x); u.y = pack2bf(v0.w, v0.z);
    u.z = pack2bf(v1.y, v1.x); u.w = pack2bf(v1.w, v1.z);
    *(uint4*)&xb[i] = u;
}

__global__ __launch_bounds__(256) void kpconv_mfma(
    const float* __restrict__ q_pts,    // [N,3]
    const float* __restrict__ s_pts,    // [M,3]
    const int*   __restrict__ inds,     // [N,32]
    const unsigned short* __restrict__ xb, // [M,4,32] bf16
    const float* __restrict__ kp,       // [15,3]
    const float* __restrict__ anchors,  // [4,3,3]
    const unsigned short* __restrict__ Wp, // [16][32][32] bf16 (permuted)
    float*       __restrict__ out)      // [N,4,32]
{
    // xa_s: [a][q][c][b_slot] bf16, 32KB; per-a 4KB slice aliased by wf after
    // GEMM1 (wave-private until barrier 2; additive column shift q*16+a*8).
    __shared__ __align__(16) unsigned short xa_s[16384];
    // nbr32: per (q,b) 16-slot bf16 A-row for the cross-MFMA; row stride 24
    // shorts (48B, keeps 16B alignment). 6 KB. Aliased by red4 after GEMM1.
    __shared__ __align__(16) unsigned short nbr32[3072];

    const int t  = threadIdx.x;
    const int n0 = blockIdx.x * 4;
    const int a = t >> 6, lane = t & 63, l15 = lane & 15, quad = lane >> 4;

    // ---- prologue: per-lane B-frag (constant) for the cross-MFMA ----
    // kdim slots: 0:k2h 1:k2l 2:Rxh 3:Rxl 4:Rxh 5:Ryh 6:Ryl 7:Ryh |
    //             8:Rzh 9:Rzl 10:Rzh 11:1 12:1 13..31:0    (R = -2*r)
    bf16x8 rkb;
    {
        float rx = 0.f, ry = 0.f, rz = 0.f, k2 = 1e30f;   // k=15 sentinel -> w=0
        if (l15 < 15) {
            const float kx = kp[l15*3+0], ky = kp[l15*3+1], kz = kp[l15*3+2];
            const float* R = anchors + a * 9;
            rx = R[0]*kx + R[1]*ky + R[2]*kz;
            ry = R[3]*kx + R[4]*ky + R[5]*kz;
            rz = R[6]*kx + R[7]*ky + R[8]*kz;
            k2 = rx*rx + ry*ry + rz*rz;
        }
        unsigned short k2h,k2l, Rxh,Rxl, Ryh,Ryl, Rzh,Rzl;
        bfsplit(k2, k2h, k2l);
        bfsplit(-2.0f*rx, Rxh, Rxl);
        bfsplit(-2.0f*ry, Ryh, Ryl);
        bfsplit(-2.0f*rz, Rzh, Rzl);
        const unsigned ONE = 0x3F80u;
        uint4 u;
        if (quad == 0) {
            u.x = (unsigned)k2h | ((unsigned)k2l << 16);
            u.y = (unsigned)Rxh | ((unsigned)Rxl << 16);
            u.z = (unsigned)Rxh | ((unsigned)Ryh << 16);
            u.w = (unsigned)Ryl | ((unsigned)Ryh << 16);
        } else if (quad == 1) {
            u.x = (unsigned)Rzh | ((unsigned)Rzl << 16);
            u.y = (unsigned)Rzh | (ONE << 16);
            u.z = ONE;
            u.w = 0u;
        } else {
            u.x = u.y = u.z = u.w = 0u;   // slots 16..31 zero -> A there is don't-care
        }
        rkb = __builtin_bit_cast(bf16x8, u);
    }

    // ---- stage nbr32 A-rows (t<128) ----
    if (t < 128) {
        const int q = t >> 5, b = t & 31;
        const int idx = inds[(n0 + q) * 32 + b];
        const float nx = s_pts[idx*3+0] - q_pts[(n0+q)*3+0];
        const float ny = s_pts[idx*3+1] - q_pts[(n0+q)*3+1];
        const float nz = s_pts[idx*3+2] - q_pts[(n0+q)*3+2];
        const float n2 = nx*nx + ny*ny + nz*nz;
        unsigned short nxh,nxl, nyh,nyl, nzh,nzl, n2h,n2l;
        bfsplit(nx, nxh, nxl); bfsplit(ny, nyh, nyl);
        bfsplit(nz, nzh, nzl); bfsplit(n2, n2h, n2l);
        const unsigned ONE = 0x3F80u;
        // A slots: 0:1 1:1 2:nxh 3:nxh 4:nxl 5:nyh 6:nyh 7:nyl |
        //          8:nzh 9:nzh 10:nzl 11:n2h 12:n2l 13..15:0
        unsigned short* p = &nbr32[(q * 32 + b) * 24];
        *(uint2*)(p)      = make_uint2(ONE | (ONE << 16),
                                       (unsigned)nxh | ((unsigned)nxh << 16));
        *(uint2*)(p + 4)  = make_uint2((unsigned)nxl | ((unsigned)nyh << 16),
                                       (unsigned)nyh | ((unsigned)nyl << 16));
        *(uint2*)(p + 8)  = make_uint2((unsigned)nzh | ((unsigned)nzh << 16),
                                       (unsigned)nzl | ((unsigned)n2h << 16));
        *(uint2*)(p + 12) = make_uint2((unsigned)n2l, 0u);
    }

    // ---- P2: gather xb -> xa_s (register transpose) ----
    // logical b = 4*bg+i -> slot = ((bg&3)^fc)*8 + (bg>>2)*4 + i, fc = c4&3.
    {
        const int c4 = t & 7, bg = (t >> 3) & 7, q = t >> 6;
        const int4 rows = *(const int4*)&inds[(n0 + q) * 32 + 4 * bg];
        const int fcs   = c4 & 3;
        const int slotb = ((bg & 3) ^ fcs) * 8 + (bg >> 2) * 4;
        unsigned short* base = &xa_s[(q * 32) * 32 + slotb];
        #pragma unroll
        for (int aa = 0; aa < 4; ++aa) {
            const uint2 r0 = *(const uint2*)&xb[rows.x * 128 + aa * 32 + c4 * 4];
            const uint2 r1 = *(const uint2*)&xb[rows.y * 128 + aa * 32 + c4 * 4];
            const uint2 r2 = *(const uint2*)&xb[rows.z * 128 + aa * 32 + c4 * 4];
            const uint2 r3 = *(const uint2*)&xb[rows.w * 128 + aa * 32 + c4 * 4];
            unsigned short* pa = base + aa * 4096;
            uint2 w;
            w.x = __builtin_amdgcn_perm(r1.x, r0.x, 0x05040100u);
            w.y = __builtin_amdgcn_perm(r3.x, r2.x, 0x05040100u);
            *(uint2*)&pa[(4 * c4 + 0) * 32] = w;
            w.x = __builtin_amdgcn_perm(r1.x, r0.x, 0x07060302u);
            w.y = __builtin_amdgcn_perm(r3.x, r2.x, 0x07060302u);
            *(uint2*)&pa[(4 * c4 + 1) * 32] = w;
            w.x = __builtin_amdgcn_perm(r1.y, r0.y, 0x05040100u);
            w.y = __builtin_amdgcn_perm(r3.y, r2.y, 0x05040100u);
            *(uint2*)&pa[(4 * c4 + 2) * 32] = w;
            w.x = __builtin_amdgcn_perm(r1.y, r0.y, 0x07060302u);
            w.y = __builtin_amdgcn_perm(r3.y, r2.y, 0x07060302u);
            *(uint2*)&pa[(4 * c4 + 3) * 32] = w;
        }
    }
    __syncthreads();   // barrier 1: xa_s + nbr32 visible

    // ---------------- GEMM1 per wave (anchor a = wave id) ----------------
    const int fc = (l15 >> 2) & 3;
    unsigned short* wfb = &xa_s[a * 4096];
    const f32x4 zacc = {0.f, 0.f, 0.f, 0.f};
    const int S = a * 8;   // + q*16 added per q below (additive column shift)

    #pragma unroll
    for (int q = 0; q < 4; ++q) {
        // cross-MFMA: sq[b][k]; quads 2-3 broadcast quads 0-1 addresses
        // (their B slots are zero -> A values are don't-care).
        const unsigned short* aX = &nbr32[(q * 32 + l15) * 24 + (quad & 1) * 8];
        const unsigned short* aY = &nbr32[(q * 32 + 16 + l15) * 24 + (quad & 1) * 8];
        const f32x4 s0 = __builtin_amdgcn_mfma_f32_16x16x32_bf16(*(const bf16x8*)aX, rkb, zacc, 0, 0, 0);
        const f32x4 s1 = __builtin_amdgcn_mfma_f32_16x16x32_bf16(*(const bf16x8*)aY, rkb, zacc, 0, 0, 0);
        // D: col k = l15, rows b = quad*4+reg (s0), 16+quad*4+reg (s1)
        float w8[8];
        #pragma unroll
        for (int j = 0; j < 4; ++j) {
            w8[j]     = fmaxf(fmaf(sqrtf(fmaxf(s0[j], 1e-12f)), -1.6666667f, 1.0f), 0.0f);
            w8[4 + j] = fmaxf(fmaf(sqrtf(fmaxf(s1[j], 1e-12f)), -1.6666667f, 1.0f), 0.0f);
        }
        uint4 uu;
        uu.x = pack2bf(w8[1], w8[0]); uu.y = pack2bf(w8[3], w8[2]);
        uu.z = pack2bf(w8[5], w8[4]); uu.w = pack2bf(w8[7], w8[6]);
        const bf16x8 afr = __builtin_bit_cast(bf16x8, uu);   // A[k=l15][b-octet(quad)]

        // GEMM1: B[b][c] from xa (slot-permuted to match), D: col c, rows k.
        const bf16x8 b0 = *(const bf16x8*)&xa_s[((a*4 + q)*32 + l15)      * 32 + 8 * (quad ^ fc)];
        const bf16x8 b1 = *(const bf16x8*)&xa_s[((a*4 + q)*32 + l15 + 16) * 32 + 8 * (quad ^ fc)];
        f32x4 d0 = zacc, d1 = zacc;
        d0 = __builtin_amdgcn_mfma_f32_16x16x32_bf16(afr, b0, d0, 0, 0, 0);
        d1 = __builtin_amdgcn_mfma_f32_16x16x32_bf16(afr, b1, d1, 0, 0, 0);
        // wf store: row q, column (kcs + q*16 + a*8) & 511, kcs = c*16 + k
        uint2 s0p, s1p;
        s0p.x = pack2bf(d0[1], d0[0]); s0p.y = pack2bf(d0[3], d0[2]);
        s1p.x = pack2bf(d1[1], d1[0]); s1p.y = pack2bf(d1[3], d1[2]);
        const int Sq = S + q * 16;
        *(uint2*)&wfb[q*512 + ((l15*16       + quad*4 + Sq) & 511)] = s0p;
        *(uint2*)&wfb[q*512 + ((l15*16 + 256 + quad*4 + Sq) & 511)] = s1p;
    }
    __syncthreads();   // barrier 2: all wf visible to all waves

    // ---------------- GEMM2 (block-wide, split across waves) ----------------
    // A rows m = a_src*4 + q (16 rows); wave w: d-tile = w&1, kk-range (w>>1)*8.
    const int tile = a & 1;
    const int kkb  = (a >> 1) * 8;
    const int a_src = l15 >> 2, qv = l15 & 3;
    const unsigned short* abase = &xa_s[a_src * 4096 + qv * 512];
    const int shf = qv * 16 + a_src * 8;
    f32x4 o = zacc;
    #pragma unroll
    for (int kk2 = 0; kk2 < 8; ++kk2) {
        const int kk = kkb + kk2;
        const bf16x8 a2 = *(const bf16x8*)&abase[(kk*32 + quad*8 + shf) & 511];
        const bf16x8 wv = *(const bf16x8*)&Wp[kk*1024 + (tile*16 + l15)*32 + quad*8];
        o = __builtin_amdgcn_mfma_f32_16x16x32_bf16(a2, wv, o, 0, 0, 0);
    }
    __syncthreads();   // barrier 3: nbr32 free -> reuse as reduction buffer
    float4* red4 = (float4*)nbr32;   // 2 KB used
    if (a >= 2) {
        red4[(a - 2) * 64 + lane] = make_float4(o[0], o[1], o[2], o[3]);
    }
    __syncthreads();   // barrier 4: partials visible
    if (a < 2) {
        const float4 p = red4[a * 64 + lane];
        o[0] += p.x; o[1] += p.y; o[2] += p.z; o[3] += p.w;
        // D rows m = quad*4+reg -> (a_out = quad, q_out = reg); col d = tile*16+l15
        #pragma unroll
        for (int r = 0; r < 4; ++r) {
            out[((n0 + r) * 4 + quad) * 32 + tile * 16 + l15] = o[r];
        }
    }
}

extern "C" void kernel_launch(void* const* d_in, const int* in_sizes, int n_in,
                              void* d_out, int out_size, void* d_ws, size_t ws_size,
                              hipStream_t stream) {
    const float* q_pts   = (const float*)d_in[0];
    const float* s_pts   = (const float*)d_in[1];
    const int*   inds    = (const int*)d_in[2];
    const float* x       = (const float*)d_in[3];
    const float* kp      = (const float*)d_in[4];
    const float* anchors = (const float*)d_in[5];
    const float* weights = (const float*)d_in[6];
    float*       out     = (float*)d_out;

    unsigned short* Wp = (unsigned short*)d_ws;                       // 32 KB
    unsigned short* xb = (unsigned short*)((char*)d_ws + (1 << 16));  // 4 MB

    prep_w<<<dim3(64),   dim3(256), 0, stream>>>(weights, Wp);
    prep_x<<<dim3(1000), dim3(256), 0, stream>>>(x, xb);
    kpconv_mfma<<<dim3(4000), dim3(256), 0, stream>>>(
        q_pts, s_pts, inds, xb, kp, anchors, Wp, out);
}

// Round 10
// 109.401 us; speedup vs baseline: 1.2191x; 1.0378x over previous
//
#include <hip/hip_runtime.h>

// KPConvInterSO3 via MFMA. N=16000, NB=32, A=4, K=15, CIN=COUT=32.
// Block = 256 threads = 4 waves; block handles 4 queries; wave w owns anchor w
// for GEMM1. GEMM2: A rows = 16 (anchor,query) pairs, split across waves by
// (d-tile, kk-range): 32 MFMA + 32 Wp loads per BLOCK. Cross-wave partial
// reduction through 2KB LDS (aliases nbr32).
// R10: barrier-3 removed (barrier 2 already orders nbr32 reads before red4
// writes); Wp B-frags hoisted into registers before barrier 1 (latency hide);
// prep kernels merged into one launch.
// Influence weights via cross-MFMA with bf16 hi/lo split (fp32-grade sq).
// x pre-converted to bf16 (4 MB, L2-resident); W pre-permuted to B-frag layout.

typedef short bf16x8 __attribute__((ext_vector_type(8)));
typedef float f32x4  __attribute__((ext_vector_type(4)));

// round-half-up bf16: 2 VALU ops. <=1 ulp vs RNE on ties.
__device__ __forceinline__ unsigned short f2bf(float f) {
    unsigned u = __builtin_bit_cast(unsigned, f);
    return (unsigned short)((u + 0x8000u) >> 16);
}
__device__ __forceinline__ float bf2f(unsigned short h) {
    return __builtin_bit_cast(float, (unsigned)h << 16);
}
// pack two floats -> (bf(hi)<<16)|bf(lo) in 3 VALU ops via v_perm_b32
__device__ __forceinline__ unsigned pack2bf(float hi, float lo) {
    unsigned uh = __builtin_bit_cast(unsigned, hi) + 0x8000u;
    unsigned ul = __builtin_bit_cast(unsigned, lo) + 0x8000u;
    return __builtin_amdgcn_perm(uh, ul, 0x07060302u);
}
// hi/lo split: v ~= bf(h) + bf(l), residual ~2^-18 rel
__device__ __forceinline__ void bfsplit(float v, unsigned short& h, unsigned short& l) {
    h = f2bf(v);
    l = f2bf(v - bf2f(h));
}

// Combined prep: blocks 0..63 build Wp (W permuted to GEMM2 B-frag layout,
// Wp[kk][d][e] = bf16(W[k][c][d]), kcs = kk*32+e = c*16+k, k=15 -> 0);
// blocks 64..1063 convert x (fp32) -> xb (bf16), 8 floats/thread.
__global__ void prep_all(const float* __restrict__ W, unsigned short* __restrict__ Wp,
                         const float* __restrict__ x, unsigned short* __restrict__ xb) {
    const int bid = blockIdx.x;
    if (bid < 64) {
        const int idx = bid * 256 + threadIdx.x;   // 0..16383
        const int kk = idx >> 10, d = (idx >> 5) & 31, e = idx & 31;
        const int kcs = kk * 32 + e;
        const int c = kcs >> 4, k = kcs & 15;
        const float v = (k < 15) ? W[(k * 32 + c) * 32 + d] : 0.0f;
        Wp[idx] = f2bf(v);
    } else {
        const int i = ((bid - 64) * 256 + threadIdx.x) * 8;
        const float4 v0 = *(const float4*)&x[i];
        const float4 v1 = *(const float4*)&x[i + 4];
        uint4 u;
        u.x = pack2bf(v0.y, v0.x); u.y = pack2bf(v0.w, v0.z);
        u.z = pack2bf(v1.y, v1.x); u.w = pack2bf(v1.w, v1.z);
        *(uint4*)&xb[i] = u;
    }
}

__global__ __launch_bounds__(256) void kpconv_mfma(
    const float* __restrict__ q_pts,    // [N,3]
    const float* __restrict__ s_pts,    // [M,3]
    const int*   __restrict__ inds,     // [N,32]
    const unsigned short* __restrict__ xb, // [M,4,32] bf16
    const float* __restrict__ kp,       // [15,3]
    const float* __restrict__ anchors,  // [4,3,3]
    const unsigned short* __restrict__ Wp, // [16][32][32] bf16 (permuted)
    float*       __restrict__ out)      // [N,4,32]
{
    // xa_s: [a][q][c][b_slot] bf16, 32KB; per-a 4KB slice aliased by wf after
    // GEMM1 (wave-private until barrier 2; additive column shift q*16+a*8).
    __shared__ __align__(16) unsigned short xa_s[16384];
    // nbr32: per (q,b) 16-slot bf16 A-row for the cross-MFMA; row stride 24
    // shorts (48B, keeps 16B alignment). 6 KB. Aliased by red4 after barrier 2.
    __shared__ __align__(16) unsigned short nbr32[3072];

    const int t  = threadIdx.x;
    const int n0 = blockIdx.x * 4;
    const int a = t >> 6, lane = t & 63, l15 = lane & 15, quad = lane >> 4;

    // ---- GEMM2 role constants + hoisted Wp B-frags (independent loads) ----
    const int tile = a & 1;            // d-tile (0: d<16, 1: d>=16)
    const int kkb  = (a >> 1) * 8;     // kk-range
    bf16x8 wreg[8];
    #pragma unroll
    for (int kk2 = 0; kk2 < 8; ++kk2) {
        wreg[kk2] = *(const bf16x8*)&Wp[(kkb + kk2) * 1024 + (tile * 16 + l15) * 32 + quad * 8];
    }

    // ---- prologue: per-lane B-frag (constant) for the cross-MFMA ----
    // kdim slots: 0:k2h 1:k2l 2:Rxh 3:Rxl 4:Rxh 5:Ryh 6:Ryl 7:Ryh |
    //             8:Rzh 9:Rzl 10:Rzh 11:1 12:1 13..31:0    (R = -2*r)
    bf16x8 rkb;
    {
        float rx = 0.f, ry = 0.f, rz = 0.f, k2 = 1e30f;   // k=15 sentinel -> w=0
        if (l15 < 15) {
            const float kx = kp[l15*3+0], ky = kp[l15*3+1], kz = kp[l15*3+2];
            const float* R = anchors + a * 9;
            rx = R[0]*kx + R[1]*ky + R[2]*kz;
            ry = R[3]*kx + R[4]*ky + R[5]*kz;
            rz = R[6]*kx + R[7]*ky + R[8]*kz;
            k2 = rx*rx + ry*ry + rz*rz;
        }
        unsigned short k2h,k2l, Rxh,Rxl, Ryh,Ryl, Rzh,Rzl;
        bfsplit(k2, k2h, k2l);
        bfsplit(-2.0f*rx, Rxh, Rxl);
        bfsplit(-2.0f*ry, Ryh, Ryl);
        bfsplit(-2.0f*rz, Rzh, Rzl);
        const unsigned ONE = 0x3F80u;
        uint4 u;
        if (quad == 0) {
            u.x = (unsigned)k2h | ((unsigned)k2l << 16);
            u.y = (unsigned)Rxh | ((unsigned)Rxl << 16);
            u.z = (unsigned)Rxh | ((unsigned)Ryh << 16);
            u.w = (unsigned)Ryl | ((unsigned)Ryh << 16);
        } else if (quad == 1) {
            u.x = (unsigned)Rzh | ((unsigned)Rzl << 16);
            u.y = (unsigned)Rzh | (ONE << 16);
            u.z = ONE;
            u.w = 0u;
        } else {
            u.x = u.y = u.z = u.w = 0u;   // B slots 16..31 zero -> A there don't-care
        }
        rkb = __builtin_bit_cast(bf16x8, u);
    }

    // ---- stage nbr32 A-rows (t<128) ----
    if (t < 128) {
        const int q = t >> 5, b = t & 31;
        const int idx = inds[(n0 + q) * 32 + b];
        const float nx = s_pts[idx*3+0] - q_pts[(n0+q)*3+0];
        const float ny = s_pts[idx*3+1] - q_pts[(n0+q)*3+1];
        const float nz = s_pts[idx*3+2] - q_pts[(n0+q)*3+2];
        const float n2 = nx*nx + ny*ny + nz*nz;
        unsigned short nxh,nxl, nyh,nyl, nzh,nzl, n2h,n2l;
        bfsplit(nx, nxh, nxl); bfsplit(ny, nyh, nyl);
        bfsplit(nz, nzh, nzl); bfsplit(n2, n2h, n2l);
        const unsigned ONE = 0x3F80u;
        // A slots: 0:1 1:1 2:nxh 3:nxh 4:nxl 5:nyh 6:nyh 7:nyl |
        //          8:nzh 9:nzh 10:nzl 11:n2h 12:n2l 13..15:0
        unsigned short* p = &nbr32[(q * 32 + b) * 24];
        *(uint2*)(p)      = make_uint2(ONE | (ONE << 16),
                                       (unsigned)nxh | ((unsigned)nxh << 16));
        *(uint2*)(p + 4)  = make_uint2((unsigned)nxl | ((unsigned)nyh << 16),
                                       (unsigned)nyh | ((unsigned)nyl << 16));
        *(uint2*)(p + 8)  = make_uint2((unsigned)nzh | ((unsigned)nzh << 16),
                                       (unsigned)nzl | ((unsigned)n2h << 16));
        *(uint2*)(p + 12) = make_uint2((unsigned)n2l, 0u);
    }

    // ---- P2: gather xb -> xa_s (register transpose) ----
    // logical b = 4*bg+i -> slot = ((bg&3)^fc)*8 + (bg>>2)*4 + i, fc = c4&3.
    {
        const int c4 = t & 7, bg = (t >> 3) & 7, q = t >> 6;
        const int4 rows = *(const int4*)&inds[(n0 + q) * 32 + 4 * bg];
        const int fcs   = c4 & 3;
        const int slotb = ((bg & 3) ^ fcs) * 8 + (bg >> 2) * 4;
        unsigned short* base = &xa_s[(q * 32) * 32 + slotb];
        #pragma unroll
        for (int aa = 0; aa < 4; ++aa) {
            const uint2 r0 = *(const uint2*)&xb[rows.x * 128 + aa * 32 + c4 * 4];
            const uint2 r1 = *(const uint2*)&xb[rows.y * 128 + aa * 32 + c4 * 4];
            const uint2 r2 = *(const uint2*)&xb[rows.z * 128 + aa * 32 + c4 * 4];
            const uint2 r3 = *(const uint2*)&xb[rows.w * 128 + aa * 32 + c4 * 4];
            unsigned short* pa = base + aa * 4096;
            uint2 w;
            w.x = __builtin_amdgcn_perm(r1.x, r0.x, 0x05040100u);
            w.y = __builtin_amdgcn_perm(r3.x, r2.x, 0x05040100u);
            *(uint2*)&pa[(4 * c4 + 0) * 32] = w;
            w.x = __builtin_amdgcn_perm(r1.x, r0.x, 0x07060302u);
            w.y = __builtin_amdgcn_perm(r3.x, r2.x, 0x07060302u);
            *(uint2*)&pa[(4 * c4 + 1) * 32] = w;
            w.x = __builtin_amdgcn_perm(r1.y, r0.y, 0x05040100u);
            w.y = __builtin_amdgcn_perm(r3.y, r2.y, 0x05040100u);
            *(uint2*)&pa[(4 * c4 + 2) * 32] = w;
            w.x = __builtin_amdgcn_perm(r1.y, r0.y, 0x07060302u);
            w.y = __builtin_amdgcn_perm(r3.y, r2.y, 0x07060302u);
            *(uint2*)&pa[(4 * c4 + 3) * 32] = w;
        }
    }
    __syncthreads();   // barrier 1: xa_s + nbr32 visible

    // ---------------- GEMM1 per wave (anchor a = wave id) ----------------
    const int fc = (l15 >> 2) & 3;
    unsigned short* wfb = &xa_s[a * 4096];
    const f32x4 zacc = {0.f, 0.f, 0.f, 0.f};
    const int S = a * 8;   // + q*16 added per q below (additive column shift)

    #pragma unroll
    for (int q = 0; q < 4; ++q) {
        // cross-MFMA: sq[b][k]; quads 2-3 broadcast quads 0-1 addresses
        // (their B slots are zero -> A values are don't-care).
        const unsigned short* aX = &nbr32[(q * 32 + l15) * 24 + (quad & 1) * 8];
        const unsigned short* aY = &nbr32[(q * 32 + 16 + l15) * 24 + (quad & 1) * 8];
        const f32x4 s0 = __builtin_amdgcn_mfma_f32_16x16x32_bf16(*(const bf16x8*)aX, rkb, zacc, 0, 0, 0);
        const f32x4 s1 = __builtin_amdgcn_mfma_f32_16x16x32_bf16(*(const bf16x8*)aY, rkb, zacc, 0, 0, 0);
        // D: col k = l15, rows b = quad*4+reg (s0), 16+quad*4+reg (s1)
        float w8[8];
        #pragma unroll
        for (int j = 0; j < 4; ++j) {
            w8[j]     = fmaxf(fmaf(sqrtf(fmaxf(s0[j], 1e-12f)), -1.6666667f, 1.0f), 0.0f);
            w8[4 + j] = fmaxf(fmaf(sqrtf(fmaxf(s1[j], 1e-12f)), -1.6666667f, 1.0f), 0.0f);
        }
        uint4 uu;
        uu.x = pack2bf(w8[1], w8[0]); uu.y = pack2bf(w8[3], w8[2]);
        uu.z = pack2bf(w8[5], w8[4]); uu.w = pack2bf(w8[7], w8[6]);
        const bf16x8 afr = __builtin_bit_cast(bf16x8, uu);   // A[k=l15][b-octet(quad)]

        // GEMM1: B[b][c] from xa (slot-permuted to match), D: col c, rows k.
        const bf16x8 b0 = *(const bf16x8*)&xa_s[((a*4 + q)*32 + l15)      * 32 + 8 * (quad ^ fc)];
        const bf16x8 b1 = *(const bf16x8*)&xa_s[((a*4 + q)*32 + l15 + 16) * 32 + 8 * (quad ^ fc)];
        f32x4 d0 = zacc, d1 = zacc;
        d0 = __builtin_amdgcn_mfma_f32_16x16x32_bf16(afr, b0, d0, 0, 0, 0);
        d1 = __builtin_amdgcn_mfma_f32_16x16x32_bf16(afr, b1, d1, 0, 0, 0);
        // wf store: row q, column (kcs + q*16 + a*8) & 511, kcs = c*16 + k
        uint2 s0p, s1p;
        s0p.x = pack2bf(d0[1], d0[0]); s0p.y = pack2bf(d0[3], d0[2]);
        s1p.x = pack2bf(d1[1], d1[0]); s1p.y = pack2bf(d1[3], d1[2]);
        const int Sq = S + q * 16;
        *(uint2*)&wfb[q*512 + ((l15*16       + quad*4 + Sq) & 511)] = s0p;
        *(uint2*)&wfb[q*512 + ((l15*16 + 256 + quad*4 + Sq) & 511)] = s1p;
    }
    __syncthreads();   // barrier 2: all wf visible; also orders nbr32 reads
                       // before the red4 writes below (no barrier 3 needed)

    // ---------------- GEMM2 (block-wide, split across waves) ----------------
    // A rows m = a_src*4 + q (16 rows); wave w: d-tile = w&1, kk-range (w>>1)*8.
    const int a_src = l15 >> 2, qv = l15 & 3;
    const unsigned short* abase = &xa_s[a_src * 4096 + qv * 512];
    const int shf = qv * 16 + a_src * 8;
    f32x4 o = zacc;
    #pragma unroll
    for (int kk2 = 0; kk2 < 8; ++kk2) {
        const bf16x8 a2 = *(const bf16x8*)&abase[((kkb + kk2)*32 + quad*8 + shf) & 511];
        o = __builtin_amdgcn_mfma_f32_16x16x32_bf16(a2, wreg[kk2], o, 0, 0, 0);
    }
    // red4 aliases nbr32 — safe: all nbr32 reads were before barrier 2.
    float4* red4 = (float4*)nbr32;   // 2 KB used
    if (a >= 2) {
        red4[(a - 2) * 64 + lane] = make_float4(o[0], o[1], o[2], o[3]);
    }
    __syncthreads();   // partials visible
    if (a < 2) {
        const float4 p = red4[a * 64 + lane];
        o[0] += p.x; o[1] += p.y; o[2] += p.z; o[3] += p.w;
        // D rows m = quad*4+reg -> (a_out = quad, q_out = reg); col d = tile*16+l15
        #pragma unroll
        for (int r = 0; r < 4; ++r) {
            out[((n0 + r) * 4 + quad) * 32 + tile * 16 + l15] = o[r];
        }
    }
}

extern "C" void kernel_launch(void* const* d_in, const int* in_sizes, int n_in,
                              void* d_out, int out_size, void* d_ws, size_t ws_size,
                              hipStream_t stream) {
    const float* q_pts   = (const float*)d_in[0];
    const float* s_pts   = (const float*)d_in[1];
    const int*   inds    = (const int*)d_in[2];
    const float* x       = (const float*)d_in[3];
    const float* kp      = (const float*)d_in[4];
    const float* anchors = (const float*)d_in[5];
    const float* weights = (const float*)d_in[6];
    float*       out     = (float*)d_out;

    unsigned short* Wp = (unsigned short*)d_ws;                       // 32 KB
    unsigned short* xb = (unsigned short*)((char*)d_ws + (1 << 16));  // 4 MB

    prep_all<<<dim3(1064), dim3(256), 0, stream>>>(weights, Wp, x, xb);
    kpconv_mfma<<<dim3(4000), dim3(256), 0, stream>>>(
        q_pts, s_pts, inds, xb, kp, anchors, Wp, out);
}